// Round 7
// baseline (246.831 us; speedup 1.0000x reference)
//
#include <hip/hip_runtime.h>
#include <stdint.h>

#define T_TOK 2048
#define HDIM  2048
#define FDIM  1024
#define NEXP  8

#define BM   128
#define BN   128
#define BK   64
#define NTHR 256
#define MT_MAX 16               // 2048 / BM
#define NT1 (FDIM / BN)         // 8
#define NT2 (HDIM / BN)         // 16
#define NK1 (HDIM / BK)         // 32
#define NK2 (FDIM / BK)         // 16
#define GRID1 (NEXP * MT_MAX * NT1)   // 1024
#define GRID2 (NEXP * MT_MAX * NT2)   // 2048

typedef unsigned short u16;
typedef __attribute__((ext_vector_type(16))) float f32x16;
typedef __attribute__((ext_vector_type(8))) short bf16x8;

__device__ __forceinline__ u16 f2bf(float f) {
  uint32_t u = __float_as_uint(f);
  u += 0x7FFFu + ((u >> 16) & 1u);   // RNE
  return (u16)(u >> 16);
}

__device__ __forceinline__ void glds16(const u16* src, u16* dst) {
  __builtin_amdgcn_global_load_lds(
      (const __attribute__((address_space(1))) uint32_t*)src,
      (__attribute__((address_space(3))) uint32_t*)dst, 16, 0, 0);
}

// ---------------------------------------------------------------------------
// Routing (order-invariant y; see R2 notes).
// ---------------------------------------------------------------------------
__global__ void route1_kernel(const float* __restrict__ logits,
                              int* __restrict__ tok_e, float* __restrict__ tok_w,
                              int* __restrict__ counts) {
  __shared__ int lcnt[NEXP];
  const int tid = threadIdx.x;
  const int t = blockIdx.x * 256 + tid;
  if (tid < NEXP) lcnt[tid] = 0;
  __syncthreads();
  float l[NEXP];
#pragma unroll
  for (int e = 0; e < NEXP; ++e) l[e] = logits[t * NEXP + e];
  float m = l[0];
#pragma unroll
  for (int e = 1; e < NEXP; ++e) m = fmaxf(m, l[e]);
  float p[NEXP]; float s = 0.f;
#pragma unroll
  for (int e = 0; e < NEXP; ++e) { p[e] = __expf(l[e] - m); s += p[e]; }
  float inv = 1.f / s;
  int i0 = 0; float p0 = p[0];
#pragma unroll
  for (int e = 1; e < NEXP; ++e) if (p[e] > p0) { p0 = p[e]; i0 = e; }
  int i1 = -1; float p1 = -1.f;
#pragma unroll
  for (int e = 0; e < NEXP; ++e) if (e != i0 && p[e] > p1) { p1 = p[e]; i1 = e; }
  tok_e[t] = i0 | (i1 << 8);
  tok_w[t * 2]     = p0 * inv;
  tok_w[t * 2 + 1] = p1 * inv;
  atomicAdd(&lcnt[i0], 1);
  atomicAdd(&lcnt[i1], 1);
  __syncthreads();
  if (tid < NEXP) atomicAdd(&counts[tid], lcnt[tid]);
}

__global__ void route2_kernel(const int* __restrict__ counts,
                              int* __restrict__ offsets, int* __restrict__ cursor) {
  if (threadIdx.x == 0) {
    int s = 0;
    for (int e = 0; e < NEXP; ++e) { offsets[e] = s; cursor[e] = s; s += counts[e]; }
    offsets[NEXP] = s;
  }
}

__global__ void route3_kernel(const int* __restrict__ tok_e, const float* __restrict__ tok_w,
                              int* __restrict__ cursor,
                              int* __restrict__ token_list, float* __restrict__ slot_w) {
  __shared__ int lcnt[NEXP], lbase[NEXP];
  const int tid = threadIdx.x;
  const int t = blockIdx.x * 256 + tid;
  if (tid < NEXP) lcnt[tid] = 0;
  __syncthreads();
  int ee = tok_e[t];
  int e0 = ee & 255, e1 = ee >> 8;
  int li0 = atomicAdd(&lcnt[e0], 1);
  int li1 = atomicAdd(&lcnt[e1], 1);
  __syncthreads();
  if (tid < NEXP) lbase[tid] = atomicAdd(&cursor[tid], lcnt[tid]);
  __syncthreads();
  int s0 = lbase[e0] + li0;
  int s1 = lbase[e1] + li1;
  token_list[s0] = t; slot_w[s0] = tok_w[t * 2];
  token_list[s1] = t; slot_w[s1] = tok_w[t * 2 + 1];
}

__global__ void convert_x_kernel(const float4* __restrict__ x, ushort4* __restrict__ xb) {
  int i = blockIdx.x * 256 + threadIdx.x;
  float4 v = x[i];
  ushort4 o;
  o.x = f2bf(v.x); o.y = f2bf(v.y); o.z = f2bf(v.z); o.w = f2bf(v.w);
  xb[i] = o;
}

// ---------------------------------------------------------------------------
// Transpose+convert ALL weights in one launch: z = which*8 + e.
// src fp32 [R][C] -> dst bf16 [C][R]. 64x64 tiles via LDS.
// ---------------------------------------------------------------------------
__global__ __launch_bounds__(256)
void tconv_all_kernel(const float* __restrict__ w1, const float* __restrict__ w3,
                      const float* __restrict__ w2,
                      u16* __restrict__ w1t, u16* __restrict__ w3t, u16* __restrict__ w2t) {
  const int z = blockIdx.z;
  const int which = z >> 3;
  const int e = z & 7;
  const float* src; u16* dst; int R, C;
  if (which == 0)      { src = w1; dst = w1t; R = HDIM; C = FDIM; }
  else if (which == 1) { src = w3; dst = w3t; R = HDIM; C = FDIM; }
  else                 { src = w2; dst = w2t; R = FDIM; C = HDIM; }
  if (blockIdx.x * 64 >= (unsigned)C || blockIdx.y * 64 >= (unsigned)R) return;
  const size_t msz = (size_t)HDIM * FDIM;
  src += (size_t)e * msz;
  dst += (size_t)e * msz;
  const int r0 = blockIdx.y * 64;
  const int c0 = blockIdx.x * 64;
  __shared__ uint32_t T[64][33];
  const int t = threadIdx.x;
  {
    const int kp = t >> 3;        // 0..31 -> rows 2kp, 2kp+1
    const int cg = t & 7;         // col group of 8
    const float* s0 = src + (size_t)(r0 + 2 * kp) * C + c0 + cg * 8;
    float4 a0 = *(const float4*)(s0);
    float4 a1 = *(const float4*)(s0 + 4);
    float4 b0 = *(const float4*)(s0 + C);
    float4 b1 = *(const float4*)(s0 + C + 4);
    T[cg * 8 + 0][kp] = (uint32_t)f2bf(a0.x) | ((uint32_t)f2bf(b0.x) << 16);
    T[cg * 8 + 1][kp] = (uint32_t)f2bf(a0.y) | ((uint32_t)f2bf(b0.y) << 16);
    T[cg * 8 + 2][kp] = (uint32_t)f2bf(a0.z) | ((uint32_t)f2bf(b0.z) << 16);
    T[cg * 8 + 3][kp] = (uint32_t)f2bf(a0.w) | ((uint32_t)f2bf(b0.w) << 16);
    T[cg * 8 + 4][kp] = (uint32_t)f2bf(a1.x) | ((uint32_t)f2bf(b1.x) << 16);
    T[cg * 8 + 5][kp] = (uint32_t)f2bf(a1.y) | ((uint32_t)f2bf(b1.y) << 16);
    T[cg * 8 + 6][kp] = (uint32_t)f2bf(a1.z) | ((uint32_t)f2bf(b1.z) << 16);
    T[cg * 8 + 7][kp] = (uint32_t)f2bf(a1.w) | ((uint32_t)f2bf(b1.w) << 16);
  }
  __syncthreads();
  {
    const int f = t >> 2;         // 0..63 (dst row c0+f)
    const int kg = t & 3;         // 16 k each
    uint32_t v[8];
#pragma unroll
    for (int i = 0; i < 8; ++i) v[i] = T[f][kg * 8 + i];
    u16* d = dst + (size_t)(c0 + f) * R + r0 + kg * 16;
    uint4 q0 = {v[0], v[1], v[2], v[3]};
    uint4 q1 = {v[4], v[5], v[6], v[7]};
    *(uint4*)(d) = q0;
    *(uint4*)(d + 8) = q1;
  }
}

// ---------------------------------------------------------------------------
// GEMM1: act[slot,f] = silu(x@w1)*(x@w3)*combine_w  (bf16 out)
// R5 schedule (reads -> barrier -> stage-issue -> MFMA; single buffer, proven
// hazard-free overlap), wave tile widened to 64x64 (BN=128): 24 ds_read_b128
// per 32 MFMAs per K-step (was 16:16) -> ~1.5x better FLOP per LDS byte.
// ---------------------------------------------------------------------------
__global__ __launch_bounds__(NTHR, 2)
void gemm1_kernel(const u16* __restrict__ Xb,
                  const u16* __restrict__ w1t,   // [E][F][H] bf16
                  const u16* __restrict__ w3t,
                  const int* __restrict__ token_list,
                  const float* __restrict__ slot_w,
                  const int* __restrict__ counts,
                  const int* __restrict__ offsets,
                  u16* __restrict__ act) {
  const int bid = blockIdx.x;
  const int e  = bid >> 7;           // / (MT_MAX*NT1)
  const int mt = (bid >> 3) & 15;
  const int nt = bid & 7;            // nt fastest: B-panel sharers 8 apart (same XCD)
  const int cnt = counts[e];
  if (mt * BM >= cnt) return;
  const int off = offsets[e];
  const int tid  = threadIdx.x;
  const int lane = tid & 63;
  const int wid  = tid >> 6;
  const int wr = wid >> 1;
  const int wc = wid & 1;

  __shared__ u16 A_lds[BM * BK];    // 16 KB  [row][64], granule^(row&7)
  __shared__ u16 B1_lds[BN * BK];   // 16 KB
  __shared__ u16 B3_lds[BN * BK];   // 16 KB

  // staging: 16 chunks of 1KB each (4/wave); chunk rows c*8 + (lane>>3)
  const u16* a_src[4];
  const u16* b1_src[4];
  const u16* b3_src[4];
#pragma unroll
  for (int i = 0; i < 4; ++i) {
    int row = (wid * 4 + i) * 8 + (lane >> 3);
    int mg = mt * BM + row;
    int mc = (mg < cnt) ? mg : (cnt - 1);
    int tok = token_list[off + mc];
    a_src[i] = Xb + (size_t)tok * HDIM + (((lane & 7) ^ (row & 7)) * 8);
    size_t rowoff = ((size_t)e * FDIM + nt * BN + row) * HDIM + (((lane & 7) ^ (row & 7)) * 8);
    b1_src[i] = w1t + rowoff;
    b3_src[i] = w3t + rowoff;
  }

  f32x16 accg[2][2] = {};
  f32x16 accu[2][2] = {};

  // prologue: stage tile 0
#pragma unroll
  for (int i = 0; i < 4; ++i) {
    glds16(a_src[i], &A_lds[(wid * 4 + i) * 512]);
    glds16(b1_src[i], &B1_lds[(wid * 4 + i) * 512]);
    glds16(b3_src[i], &B3_lds[(wid * 4 + i) * 512]);
  }

#pragma unroll 1
  for (int t = 0; t < NK1; ++t) {
    __syncthreads();   // stage(t) drained -> tile t visible
    bf16x8 af[2][4], bg[2][4], bu[2][4];
#pragma unroll
    for (int m = 0; m < 2; ++m) {
      int R = wr * 64 + m * 32 + (lane & 31);
#pragma unroll
      for (int kk = 0; kk < 4; ++kk) {
        int gl = kk * 2 + (lane >> 5);
        af[m][kk] = *(const bf16x8*)&A_lds[R * BK + ((gl ^ (R & 7)) * 8)];
      }
    }
#pragma unroll
    for (int n = 0; n < 2; ++n) {
      int R = wc * 64 + n * 32 + (lane & 31);
#pragma unroll
      for (int kk = 0; kk < 4; ++kk) {
        int gl = kk * 2 + (lane >> 5);
        int pos = R * BK + ((gl ^ (R & 7)) * 8);
        bg[n][kk] = *(const bf16x8*)&B1_lds[pos];
        bu[n][kk] = *(const bf16x8*)&B3_lds[pos];
      }
    }
    __syncthreads();   // all reads complete -> safe to overwrite
    if (t + 1 < NK1) { // in flight across MFMA phase; drained at next top-barrier
      const int ks = (t + 1) * BK;
#pragma unroll
      for (int i = 0; i < 4; ++i) {
        glds16(a_src[i] + ks, &A_lds[(wid * 4 + i) * 512]);
        glds16(b1_src[i] + ks, &B1_lds[(wid * 4 + i) * 512]);
        glds16(b3_src[i] + ks, &B3_lds[(wid * 4 + i) * 512]);
      }
    }
#pragma unroll
    for (int kk = 0; kk < 4; ++kk)
#pragma unroll
      for (int m = 0; m < 2; ++m)
#pragma unroll
        for (int n = 0; n < 2; ++n) {
          accg[m][n] = __builtin_amdgcn_mfma_f32_32x32x16_bf16(af[m][kk], bg[n][kk], accg[m][n], 0, 0, 0);
          accu[m][n] = __builtin_amdgcn_mfma_f32_32x32x16_bf16(af[m][kk], bu[n][kk], accu[m][n], 0, 0, 0);
        }
  }

  // epilogue. 32x32 C/D: col=lane&31, row=(reg&3)+8*(reg>>2)+4*(lane>>5)
#pragma unroll
  for (int m = 0; m < 2; ++m) {
    int base = mt * BM + wr * 64 + m * 32 + 4 * (lane >> 5);
#pragma unroll
    for (int reg = 0; reg < 16; ++reg) {
      int mg = base + (reg & 3) + 8 * (reg >> 2);
      if (mg < cnt) {
        int slot = off + mg;
        float wgt = slot_w[slot];
#pragma unroll
        for (int n = 0; n < 2; ++n) {
          int fcol = nt * BN + wc * 64 + n * 32 + (lane & 31);
          float g = accg[m][n][reg];
          float u = accu[m][n][reg];
          float sv = g / (1.f + __expf(-g));
          act[(size_t)slot * FDIM + fcol] = f2bf(sv * u * wgt);
        }
      }
    }
  }
}

// ---------------------------------------------------------------------------
// GEMM2: y[token,h] += act[slot,:] @ w2t[e]  (fp32 atomics, 2 addends/elem)
// Same structure, wave tile 64x64.
// ---------------------------------------------------------------------------
__global__ __launch_bounds__(NTHR, 2)
void gemm2_kernel(const u16* __restrict__ act,
                  const u16* __restrict__ w2t,   // [E][H][F] bf16
                  const int* __restrict__ token_list,
                  const int* __restrict__ counts,
                  const int* __restrict__ offsets,
                  float* __restrict__ y) {
  const int bid = blockIdx.x;
  const int e  = bid >> 8;           // / (MT_MAX*NT2)
  const int mt = (bid >> 4) & 15;
  const int nt = bid & 15;
  const int cnt = counts[e];
  if (mt * BM >= cnt) return;
  const int off = offsets[e];
  const int tid  = threadIdx.x;
  const int lane = tid & 63;
  const int wid  = tid >> 6;
  const int wr = wid >> 1;
  const int wc = wid & 1;

  __shared__ u16 A_lds[BM * BK];   // 16 KB
  __shared__ u16 B_lds[BN * BK];   // 16 KB

  const u16* a_src[4];
  const u16* b_src[4];
#pragma unroll
  for (int i = 0; i < 4; ++i) {
    int row = (wid * 4 + i) * 8 + (lane >> 3);
    int mg = mt * BM + row;
    int mc = (mg < cnt) ? mg : (cnt - 1);
    a_src[i] = act + (size_t)(off + mc) * FDIM + (((lane & 7) ^ (row & 7)) * 8);
    b_src[i] = w2t + ((size_t)e * HDIM + nt * BN + row) * FDIM + (((lane & 7) ^ (row & 7)) * 8);
  }

  f32x16 acc[2][2] = {};

#pragma unroll
  for (int i = 0; i < 4; ++i) {
    glds16(a_src[i], &A_lds[(wid * 4 + i) * 512]);
    glds16(b_src[i], &B_lds[(wid * 4 + i) * 512]);
  }

#pragma unroll 1
  for (int t = 0; t < NK2; ++t) {
    __syncthreads();
    bf16x8 af[2][4], bb[2][4];
#pragma unroll
    for (int m = 0; m < 2; ++m) {
      int R = wr * 64 + m * 32 + (lane & 31);
#pragma unroll
      for (int kk = 0; kk < 4; ++kk) {
        int gl = kk * 2 + (lane >> 5);
        af[m][kk] = *(const bf16x8*)&A_lds[R * BK + ((gl ^ (R & 7)) * 8)];
      }
    }
#pragma unroll
    for (int n = 0; n < 2; ++n) {
      int R = wc * 64 + n * 32 + (lane & 31);
#pragma unroll
      for (int kk = 0; kk < 4; ++kk) {
        int gl = kk * 2 + (lane >> 5);
        bb[n][kk] = *(const bf16x8*)&B_lds[R * BK + ((gl ^ (R & 7)) * 8)];
      }
    }
    __syncthreads();
    if (t + 1 < NK2) {
      const int ks = (t + 1) * BK;
#pragma unroll
      for (int i = 0; i < 4; ++i) {
        glds16(a_src[i] + ks, &A_lds[(wid * 4 + i) * 512]);
        glds16(b_src[i] + ks, &B_lds[(wid * 4 + i) * 512]);
      }
    }
#pragma unroll
    for (int kk = 0; kk < 4; ++kk)
#pragma unroll
      for (int m = 0; m < 2; ++m)
#pragma unroll
        for (int n = 0; n < 2; ++n)
          acc[m][n] = __builtin_amdgcn_mfma_f32_32x32x16_bf16(af[m][kk], bb[n][kk], acc[m][n], 0, 0, 0);
  }

#pragma unroll
  for (int m = 0; m < 2; ++m) {
    int base = mt * BM + wr * 64 + m * 32 + 4 * (lane >> 5);
#pragma unroll
    for (int reg = 0; reg < 16; ++reg) {
      int mg = base + (reg & 3) + 8 * (reg >> 2);
      if (mg < cnt) {
        int slot = off + mg;
        int tok = token_list[slot];
#pragma unroll
        for (int n = 0; n < 2; ++n) {
          int hcol = nt * BN + wc * 64 + n * 32 + (lane & 31);
          unsafeAtomicAdd(y + (size_t)tok * HDIM + hcol, acc[m][n][reg]);
        }
      }
    }
  }
}

// ---------------------------------------------------------------------------
extern "C" void kernel_launch(void* const* d_in, const int* in_sizes, int n_in,
                              void* d_out, int out_size, void* d_ws, size_t ws_size,
                              hipStream_t stream) {
  (void)in_sizes; (void)n_in; (void)out_size; (void)ws_size;
  const float* hs     = (const float*)d_in[0];
  const float* logits = (const float*)d_in[1];
  const float* w1     = (const float*)d_in[2];
  const float* w3     = (const float*)d_in[3];
  const float* w2     = (const float*)d_in[4];
  float* y = (float*)d_out;

  uint8_t* ws = (uint8_t*)d_ws;
  int*   token_list = (int*)(ws);
  float* slot_w     = (float*)(ws + (16 << 10));
  int*   counts     = (int*)(ws + (32 << 10));
  int*   offsets    = (int*)(ws + (32 << 10) + 128);
  int*   cursor     = (int*)(ws + (32 << 10) + 256);
  int*   tok_e      = (int*)(ws + (33 << 10));
  float* tok_w      = (float*)(ws + (42 << 10));
  const size_t MB = 1 << 20;
  u16*   Xb  = (u16*)(ws + (64 << 10));                 // 8 MB
  u16*   act = (u16*)(ws + (64 << 10) + 8 * MB);        // 8 MB
  u16*   w1t = (u16*)(ws + (64 << 10) + 16 * MB);       // 32 MB [E][F][H]
  u16*   w3t = (u16*)(ws + (64 << 10) + 48 * MB);       // 32 MB [E][F][H]
  u16*   w2t = (u16*)(ws + (64 << 10) + 80 * MB);       // 32 MB [E][H][F]

  hipMemsetAsync(counts, 0, NEXP * sizeof(int), stream);
  route1_kernel<<<T_TOK / 256, 256, 0, stream>>>(logits, tok_e, tok_w, counts);
  route2_kernel<<<1, 64, 0, stream>>>(counts, offsets, cursor);
  route3_kernel<<<T_TOK / 256, 256, 0, stream>>>(tok_e, tok_w, cursor, token_list, slot_w);
  convert_x_kernel<<<(T_TOK * HDIM / 4) / 256, 256, 0, stream>>>((const float4*)hs, (ushort4*)Xb);
  tconv_all_kernel<<<dim3(32, 32, 24), 256, 0, stream>>>(w1, w3, w2, w1t, w3t, w2t);
  hipMemsetAsync(d_out, 0, (size_t)T_TOK * HDIM * sizeof(float), stream);
  gemm1_kernel<<<GRID1, NTHR, 0, stream>>>(Xb, w1t, w3t, token_list, slot_w, counts, offsets, act);
  gemm2_kernel<<<GRID2, NTHR, 0, stream>>>(act, w2t, token_list, counts, offsets, y);
}

// Round 8
// 195.789 us; speedup vs baseline: 1.2607x; 1.2607x over previous
//
#include <hip/hip_runtime.h>
#include <stdint.h>

#define T_TOK 2048
#define HDIM  2048
#define FDIM  1024
#define NEXP  8

#define BM   128
#define BK   64
#define NTHR 256
#define MT_MAX 16                 // 2048 / BM
#define BN1  64
#define BN2  128
#define NT1 (FDIM / BN1)          // 16
#define NT2 (HDIM / BN2)          // 16
#define NK1 (HDIM / BK)           // 32
#define NK2 (FDIM / BK)           // 16
#define GRID1 (NEXP * MT_MAX * NT1)   // 2048
#define GRID2 (NEXP * MT_MAX * NT2)   // 2048

typedef unsigned short u16;
typedef __attribute__((ext_vector_type(16))) float f32x16;
typedef __attribute__((ext_vector_type(8))) short bf16x8;

__device__ __forceinline__ u16 f2bf(float f) {
  uint32_t u = __float_as_uint(f);
  u += 0x7FFFu + ((u >> 16) & 1u);   // RNE
  return (u16)(u >> 16);
}

__device__ __forceinline__ void glds16(const u16* src, u16* dst) {
  __builtin_amdgcn_global_load_lds(
      (const __attribute__((address_space(1))) uint32_t*)src,
      (__attribute__((address_space(3))) uint32_t*)dst, 16, 0, 0);
}

// ---------------------------------------------------------------------------
// Routing (order-invariant y; see R2 notes).
// ---------------------------------------------------------------------------
__global__ void route1_kernel(const float* __restrict__ logits,
                              int* __restrict__ tok_e, float* __restrict__ tok_w,
                              int* __restrict__ counts) {
  __shared__ int lcnt[NEXP];
  const int tid = threadIdx.x;
  const int t = blockIdx.x * 256 + tid;
  if (tid < NEXP) lcnt[tid] = 0;
  __syncthreads();
  float l[NEXP];
#pragma unroll
  for (int e = 0; e < NEXP; ++e) l[e] = logits[t * NEXP + e];
  float m = l[0];
#pragma unroll
  for (int e = 1; e < NEXP; ++e) m = fmaxf(m, l[e]);
  float p[NEXP]; float s = 0.f;
#pragma unroll
  for (int e = 0; e < NEXP; ++e) { p[e] = __expf(l[e] - m); s += p[e]; }
  float inv = 1.f / s;
  int i0 = 0; float p0 = p[0];
#pragma unroll
  for (int e = 1; e < NEXP; ++e) if (p[e] > p0) { p0 = p[e]; i0 = e; }
  int i1 = -1; float p1 = -1.f;
#pragma unroll
  for (int e = 0; e < NEXP; ++e) if (e != i0 && p[e] > p1) { p1 = p[e]; i1 = e; }
  tok_e[t] = i0 | (i1 << 8);
  tok_w[t * 2]     = p0 * inv;
  tok_w[t * 2 + 1] = p1 * inv;
  atomicAdd(&lcnt[i0], 1);
  atomicAdd(&lcnt[i1], 1);
  __syncthreads();
  if (tid < NEXP) atomicAdd(&counts[tid], lcnt[tid]);
}

__global__ void route2_kernel(const int* __restrict__ counts,
                              int* __restrict__ offsets, int* __restrict__ cursor) {
  if (threadIdx.x == 0) {
    int s = 0;
    for (int e = 0; e < NEXP; ++e) { offsets[e] = s; cursor[e] = s; s += counts[e]; }
    offsets[NEXP] = s;
  }
}

__global__ void route3_kernel(const int* __restrict__ tok_e, const float* __restrict__ tok_w,
                              int* __restrict__ cursor,
                              int* __restrict__ token_list, float* __restrict__ slot_w) {
  __shared__ int lcnt[NEXP], lbase[NEXP];
  const int tid = threadIdx.x;
  const int t = blockIdx.x * 256 + tid;
  if (tid < NEXP) lcnt[tid] = 0;
  __syncthreads();
  int ee = tok_e[t];
  int e0 = ee & 255, e1 = ee >> 8;
  int li0 = atomicAdd(&lcnt[e0], 1);
  int li1 = atomicAdd(&lcnt[e1], 1);
  __syncthreads();
  if (tid < NEXP) lbase[tid] = atomicAdd(&cursor[tid], lcnt[tid]);
  __syncthreads();
  int s0 = lbase[e0] + li0;
  int s1 = lbase[e1] + li1;
  token_list[s0] = t; slot_w[s0] = tok_w[t * 2];
  token_list[s1] = t; slot_w[s1] = tok_w[t * 2 + 1];
}

__global__ void convert_x_kernel(const float4* __restrict__ x, ushort4* __restrict__ xb) {
  int i = blockIdx.x * 256 + threadIdx.x;
  float4 v = x[i];
  ushort4 o;
  o.x = f2bf(v.x); o.y = f2bf(v.y); o.z = f2bf(v.z); o.w = f2bf(v.w);
  xb[i] = o;
}

// ---------------------------------------------------------------------------
// Transpose+convert ALL weights in one launch: z = which*8 + e.
// src fp32 [R][C] -> dst bf16 [C][R]. 64x64 tiles via LDS.
// ---------------------------------------------------------------------------
__global__ __launch_bounds__(256)
void tconv_all_kernel(const float* __restrict__ w1, const float* __restrict__ w3,
                      const float* __restrict__ w2,
                      u16* __restrict__ w1t, u16* __restrict__ w3t, u16* __restrict__ w2t) {
  const int z = blockIdx.z;
  const int which = z >> 3;
  const int e = z & 7;
  const float* src; u16* dst; int R, C;
  if (which == 0)      { src = w1; dst = w1t; R = HDIM; C = FDIM; }
  else if (which == 1) { src = w3; dst = w3t; R = HDIM; C = FDIM; }
  else                 { src = w2; dst = w2t; R = FDIM; C = HDIM; }
  if (blockIdx.x * 64 >= (unsigned)C || blockIdx.y * 64 >= (unsigned)R) return;
  const size_t msz = (size_t)HDIM * FDIM;
  src += (size_t)e * msz;
  dst += (size_t)e * msz;
  const int r0 = blockIdx.y * 64;
  const int c0 = blockIdx.x * 64;
  __shared__ uint32_t T[64][33];
  const int t = threadIdx.x;
  {
    const int kp = t >> 3;        // 0..31 -> rows 2kp, 2kp+1
    const int cg = t & 7;         // col group of 8
    const float* s0 = src + (size_t)(r0 + 2 * kp) * C + c0 + cg * 8;
    float4 a0 = *(const float4*)(s0);
    float4 a1 = *(const float4*)(s0 + 4);
    float4 b0 = *(const float4*)(s0 + C);
    float4 b1 = *(const float4*)(s0 + C + 4);
    T[cg * 8 + 0][kp] = (uint32_t)f2bf(a0.x) | ((uint32_t)f2bf(b0.x) << 16);
    T[cg * 8 + 1][kp] = (uint32_t)f2bf(a0.y) | ((uint32_t)f2bf(b0.y) << 16);
    T[cg * 8 + 2][kp] = (uint32_t)f2bf(a0.z) | ((uint32_t)f2bf(b0.z) << 16);
    T[cg * 8 + 3][kp] = (uint32_t)f2bf(a0.w) | ((uint32_t)f2bf(b0.w) << 16);
    T[cg * 8 + 4][kp] = (uint32_t)f2bf(a1.x) | ((uint32_t)f2bf(b1.x) << 16);
    T[cg * 8 + 5][kp] = (uint32_t)f2bf(a1.y) | ((uint32_t)f2bf(b1.y) << 16);
    T[cg * 8 + 6][kp] = (uint32_t)f2bf(a1.z) | ((uint32_t)f2bf(b1.z) << 16);
    T[cg * 8 + 7][kp] = (uint32_t)f2bf(a1.w) | ((uint32_t)f2bf(b1.w) << 16);
  }
  __syncthreads();
  {
    const int f = t >> 2;         // 0..63 (dst row c0+f)
    const int kg = t & 3;         // 16 k each
    uint32_t v[8];
#pragma unroll
    for (int i = 0; i < 8; ++i) v[i] = T[f][kg * 8 + i];
    u16* d = dst + (size_t)(c0 + f) * R + r0 + kg * 16;
    uint4 q0 = {v[0], v[1], v[2], v[3]};
    uint4 q1 = {v[4], v[5], v[6], v[7]};
    *(uint4*)(d) = q0;
    *(uint4*)(d + 8) = q1;
  }
}

// ---------------------------------------------------------------------------
// GEMM1 (verbatim round-5 measured config, 68.5us): BM=128 BN=64 BK=64,
// 4 waves, wave tile 64x32 (dual-B), single-buffer, reads -> barrier ->
// stage-issue -> MFMA (hazard-free overlap; stage drains at next top barrier).
// ---------------------------------------------------------------------------
__global__ __launch_bounds__(NTHR, 3)
void gemm1_kernel(const u16* __restrict__ Xb,
                  const u16* __restrict__ w1t,   // [E][F][H] bf16
                  const u16* __restrict__ w3t,
                  const int* __restrict__ token_list,
                  const float* __restrict__ slot_w,
                  const int* __restrict__ counts,
                  const int* __restrict__ offsets,
                  u16* __restrict__ act) {
  const int bid = blockIdx.x;
  const int e  = bid >> 8;
  const int mt = (bid >> 4) & 15;
  const int nt = bid & 15;
  const int cnt = counts[e];
  if (mt * BM >= cnt) return;
  const int off = offsets[e];
  const int tid  = threadIdx.x;
  const int lane = tid & 63;
  const int wid  = tid >> 6;
  const int wr = wid >> 1;       // 0..1 (m half)
  const int wc = wid & 1;        // 0..1 (n half)

  __shared__ u16 A_lds[BM * BK];     // 16 KB  [row][64], granule^(row&7)
  __shared__ u16 B1_lds[BN1 * BK];   // 8 KB
  __shared__ u16 B3_lds[BN1 * BK];   // 8 KB

  const u16* a_src[4];
#pragma unroll
  for (int i = 0; i < 4; ++i) {
    int row = (wid * 4 + i) * 8 + (lane >> 3);
    int mg = mt * BM + row;
    int mc = (mg < cnt) ? mg : (cnt - 1);
    int tok = token_list[off + mc];
    a_src[i] = Xb + (size_t)tok * HDIM + (((lane & 7) ^ (row & 7)) * 8);
  }
  const u16* b1_src[2];
  const u16* b3_src[2];
#pragma unroll
  for (int i = 0; i < 2; ++i) {
    int n = (wid * 2 + i) * 8 + (lane >> 3);
    size_t rowoff = ((size_t)e * FDIM + nt * BN1 + n) * HDIM + (((lane & 7) ^ (n & 7)) * 8);
    b1_src[i] = w1t + rowoff;
    b3_src[i] = w3t + rowoff;
  }

  f32x16 accg[2] = {};
  f32x16 accu[2] = {};

#pragma unroll
  for (int i = 0; i < 4; ++i) glds16(a_src[i], &A_lds[(wid * 4 + i) * 512]);
#pragma unroll
  for (int i = 0; i < 2; ++i) {
    glds16(b1_src[i], &B1_lds[(wid * 2 + i) * 512]);
    glds16(b3_src[i], &B3_lds[(wid * 2 + i) * 512]);
  }

#pragma unroll 1
  for (int t = 0; t < NK1; ++t) {
    __syncthreads();   // stage(t) drained -> tile t visible
    bf16x8 af[2][4], bg[4], bu[4];
#pragma unroll
    for (int m = 0; m < 2; ++m) {
      int R = wr * 64 + m * 32 + (lane & 31);
#pragma unroll
      for (int kk = 0; kk < 4; ++kk) {
        int gl = kk * 2 + (lane >> 5);
        af[m][kk] = *(const bf16x8*)&A_lds[R * BK + ((gl ^ (R & 7)) * 8)];
      }
    }
    {
      int R = wc * 32 + (lane & 31);
#pragma unroll
      for (int kk = 0; kk < 4; ++kk) {
        int gl = kk * 2 + (lane >> 5);
        int pos = R * BK + ((gl ^ (R & 7)) * 8);
        bg[kk] = *(const bf16x8*)&B1_lds[pos];
        bu[kk] = *(const bf16x8*)&B3_lds[pos];
      }
    }
    __syncthreads();   // all reads complete -> safe to overwrite
    if (t + 1 < NK1) { // in flight across MFMA phase; drained at next top barrier
      const int ks = (t + 1) * BK;
#pragma unroll
      for (int i = 0; i < 4; ++i) glds16(a_src[i] + ks, &A_lds[(wid * 4 + i) * 512]);
#pragma unroll
      for (int i = 0; i < 2; ++i) {
        glds16(b1_src[i] + ks, &B1_lds[(wid * 2 + i) * 512]);
        glds16(b3_src[i] + ks, &B3_lds[(wid * 2 + i) * 512]);
      }
    }
#pragma unroll
    for (int m = 0; m < 2; ++m)
#pragma unroll
      for (int kk = 0; kk < 4; ++kk) {
        accg[m] = __builtin_amdgcn_mfma_f32_32x32x16_bf16(af[m][kk], bg[kk], accg[m], 0, 0, 0);
        accu[m] = __builtin_amdgcn_mfma_f32_32x32x16_bf16(af[m][kk], bu[kk], accu[m], 0, 0, 0);
      }
  }

  // epilogue. 32x32 C/D: col=lane&31, row=(reg&3)+8*(reg>>2)+4*(lane>>5)
  const int fcol = nt * BN1 + wc * 32 + (lane & 31);
#pragma unroll
  for (int m = 0; m < 2; ++m) {
    int base = mt * BM + wr * 64 + m * 32 + 4 * (lane >> 5);
#pragma unroll
    for (int reg = 0; reg < 16; ++reg) {
      int mg = base + (reg & 3) + 8 * (reg >> 2);
      if (mg < cnt) {
        int slot = off + mg;
        float wgt = slot_w[slot];
        float g = accg[m][reg];
        float u = accu[m][reg];
        float sv = g / (1.f + __expf(-g));
        act[(size_t)slot * FDIM + fcol] = f2bf(sv * u * wgt);
      }
    }
  }
}

// ---------------------------------------------------------------------------
// GEMM2: y[token,h] += act[slot,:] @ w2t[e].  Single-B twin of gemm1's
// profile: BM=128 BN=128 BK=64, wave tile 64x64, 16 b128 reads : 16 MFMA,
// 512 real blocks. Same proven schedule.
// ---------------------------------------------------------------------------
__global__ __launch_bounds__(NTHR, 3)
void gemm2_kernel(const u16* __restrict__ act,
                  const u16* __restrict__ w2t,   // [E][H][F] bf16
                  const int* __restrict__ token_list,
                  const int* __restrict__ counts,
                  const int* __restrict__ offsets,
                  float* __restrict__ y) {
  const int bid = blockIdx.x;
  const int e  = bid >> 8;
  const int mt = (bid >> 4) & 15;
  const int nt = bid & 15;
  const int cnt = counts[e];
  if (mt * BM >= cnt) return;
  const int off = offsets[e];
  const int tid  = threadIdx.x;
  const int lane = tid & 63;
  const int wid  = tid >> 6;
  const int wr = wid >> 1;
  const int wc = wid & 1;

  __shared__ u16 A_lds[BM * BK];     // 16 KB
  __shared__ u16 B_lds[BN2 * BK];    // 16 KB

  const u16* a_src[4];
  const u16* b_src[4];
#pragma unroll
  for (int i = 0; i < 4; ++i) {
    int row = (wid * 4 + i) * 8 + (lane >> 3);
    int mg = mt * BM + row;
    int mc = (mg < cnt) ? mg : (cnt - 1);
    a_src[i] = act + (size_t)(off + mc) * FDIM + (((lane & 7) ^ (row & 7)) * 8);
    b_src[i] = w2t + ((size_t)e * HDIM + nt * BN2 + row) * FDIM + (((lane & 7) ^ (row & 7)) * 8);
  }

  f32x16 acc[2][2] = {};

#pragma unroll
  for (int i = 0; i < 4; ++i) {
    glds16(a_src[i], &A_lds[(wid * 4 + i) * 512]);
    glds16(b_src[i], &B_lds[(wid * 4 + i) * 512]);
  }

#pragma unroll 1
  for (int t = 0; t < NK2; ++t) {
    __syncthreads();
    bf16x8 af[2][4], bb[2][4];
#pragma unroll
    for (int m = 0; m < 2; ++m) {
      int R = wr * 64 + m * 32 + (lane & 31);
#pragma unroll
      for (int kk = 0; kk < 4; ++kk) {
        int gl = kk * 2 + (lane >> 5);
        af[m][kk] = *(const bf16x8*)&A_lds[R * BK + ((gl ^ (R & 7)) * 8)];
      }
    }
#pragma unroll
    for (int n = 0; n < 2; ++n) {
      int R = wc * 64 + n * 32 + (lane & 31);
#pragma unroll
      for (int kk = 0; kk < 4; ++kk) {
        int gl = kk * 2 + (lane >> 5);
        bb[n][kk] = *(const bf16x8*)&B_lds[R * BK + ((gl ^ (R & 7)) * 8)];
      }
    }
    __syncthreads();
    if (t + 1 < NK2) {
      const int ks = (t + 1) * BK;
#pragma unroll
      for (int i = 0; i < 4; ++i) {
        glds16(a_src[i] + ks, &A_lds[(wid * 4 + i) * 512]);
        glds16(b_src[i] + ks, &B_lds[(wid * 4 + i) * 512]);
      }
    }
#pragma unroll
    for (int kk = 0; kk < 4; ++kk)
#pragma unroll
      for (int m = 0; m < 2; ++m)
#pragma unroll
        for (int n = 0; n < 2; ++n)
          acc[m][n] = __builtin_amdgcn_mfma_f32_32x32x16_bf16(af[m][kk], bb[n][kk], acc[m][n], 0, 0, 0);
  }

#pragma unroll
  for (int m = 0; m < 2; ++m) {
    int base = mt * BM + wr * 64 + m * 32 + 4 * (lane >> 5);
#pragma unroll
    for (int reg = 0; reg < 16; ++reg) {
      int mg = base + (reg & 3) + 8 * (reg >> 2);
      if (mg < cnt) {
        int slot = off + mg;
        int tok = token_list[slot];
#pragma unroll
        for (int n = 0; n < 2; ++n) {
          int hcol = nt * BN2 + wc * 64 + n * 32 + (lane & 31);
          unsafeAtomicAdd(y + (size_t)tok * HDIM + hcol, acc[m][n][reg]);
        }
      }
    }
  }
}

// ---------------------------------------------------------------------------
extern "C" void kernel_launch(void* const* d_in, const int* in_sizes, int n_in,
                              void* d_out, int out_size, void* d_ws, size_t ws_size,
                              hipStream_t stream) {
  (void)in_sizes; (void)n_in; (void)out_size; (void)ws_size;
  const float* hs     = (const float*)d_in[0];
  const float* logits = (const float*)d_in[1];
  const float* w1     = (const float*)d_in[2];
  const float* w3     = (const float*)d_in[3];
  const float* w2     = (const float*)d_in[4];
  float* y = (float*)d_out;

  uint8_t* ws = (uint8_t*)d_ws;
  int*   token_list = (int*)(ws);
  float* slot_w     = (float*)(ws + (16 << 10));
  int*   counts     = (int*)(ws + (32 << 10));
  int*   offsets    = (int*)(ws + (32 << 10) + 128);
  int*   cursor     = (int*)(ws + (32 << 10) + 256);
  int*   tok_e      = (int*)(ws + (33 << 10));
  float* tok_w      = (float*)(ws + (42 << 10));
  const size_t MB = 1 << 20;
  u16*   Xb  = (u16*)(ws + (64 << 10));                 // 8 MB
  u16*   act = (u16*)(ws + (64 << 10) + 8 * MB);        // 8 MB
  u16*   w1t = (u16*)(ws + (64 << 10) + 16 * MB);       // 32 MB [E][F][H]
  u16*   w3t = (u16*)(ws + (64 << 10) + 48 * MB);       // 32 MB [E][F][H]
  u16*   w2t = (u16*)(ws + (64 << 10) + 80 * MB);       // 32 MB [E][H][F]

  hipMemsetAsync(counts, 0, NEXP * sizeof(int), stream);
  route1_kernel<<<T_TOK / 256, 256, 0, stream>>>(logits, tok_e, tok_w, counts);
  route2_kernel<<<1, 64, 0, stream>>>(counts, offsets, cursor);
  route3_kernel<<<T_TOK / 256, 256, 0, stream>>>(tok_e, tok_w, cursor, token_list, slot_w);
  convert_x_kernel<<<(T_TOK * HDIM / 4) / 256, 256, 0, stream>>>((const float4*)hs, (ushort4*)Xb);
  tconv_all_kernel<<<dim3(32, 32, 24), 256, 0, stream>>>(w1, w3, w2, w1t, w3t, w2t);
  hipMemsetAsync(d_out, 0, (size_t)T_TOK * HDIM * sizeof(float), stream);
  gemm1_kernel<<<GRID1, NTHR, 0, stream>>>(Xb, w1t, w3t, token_list, slot_w, counts, offsets, act);
  gemm2_kernel<<<GRID2, NTHR, 0, stream>>>(act, w2t, token_list, counts, offsets, y);
}

// Round 9
// 186.119 us; speedup vs baseline: 1.3262x; 1.0520x over previous
//
#include <hip/hip_runtime.h>
#include <stdint.h>

#define T_TOK 2048
#define HDIM  2048
#define FDIM  1024
#define NEXP  8

#define BM   128
#define BK   64
#define NTHR 256
#define MT_MAX 16                 // 2048 / BM
#define BN1  64
#define BN2  128
#define NT1 (FDIM / BN1)          // 16
#define NT2 (HDIM / BN2)          // 16
#define NK1 (HDIM / BK)           // 32
#define NK2 (FDIM / BK)           // 16
#define GRID1 (NEXP * MT_MAX * NT1)   // 2048
#define GRID2 (NEXP * MT_MAX * NT2)   // 2048

typedef unsigned short u16;
typedef __attribute__((ext_vector_type(16))) float f32x16;
typedef __attribute__((ext_vector_type(8))) short bf16x8;

__device__ __forceinline__ u16 f2bf(float f) {
  uint32_t u = __float_as_uint(f);
  u += 0x7FFFu + ((u >> 16) & 1u);   // RNE
  return (u16)(u >> 16);
}

__device__ __forceinline__ uint32_t pack2(float lo, float hi) {
  return (uint32_t)f2bf(lo) | ((uint32_t)f2bf(hi) << 16);
}

__device__ __forceinline__ void glds16(const u16* src, u16* dst) {
  __builtin_amdgcn_global_load_lds(
      (const __attribute__((address_space(1))) uint32_t*)src,
      (__attribute__((address_space(3))) uint32_t*)dst, 16, 0, 0);
}

// ---------------------------------------------------------------------------
// Routing (order-invariant y; see R2 notes).
// ---------------------------------------------------------------------------
__global__ void route1_kernel(const float* __restrict__ logits,
                              int* __restrict__ tok_e, float* __restrict__ tok_w,
                              int* __restrict__ counts) {
  __shared__ int lcnt[NEXP];
  const int tid = threadIdx.x;
  const int t = blockIdx.x * 256 + tid;
  if (tid < NEXP) lcnt[tid] = 0;
  __syncthreads();
  float l[NEXP];
#pragma unroll
  for (int e = 0; e < NEXP; ++e) l[e] = logits[t * NEXP + e];
  float m = l[0];
#pragma unroll
  for (int e = 1; e < NEXP; ++e) m = fmaxf(m, l[e]);
  float p[NEXP]; float s = 0.f;
#pragma unroll
  for (int e = 0; e < NEXP; ++e) { p[e] = __expf(l[e] - m); s += p[e]; }
  float inv = 1.f / s;
  int i0 = 0; float p0 = p[0];
#pragma unroll
  for (int e = 1; e < NEXP; ++e) if (p[e] > p0) { p0 = p[e]; i0 = e; }
  int i1 = -1; float p1 = -1.f;
#pragma unroll
  for (int e = 0; e < NEXP; ++e) if (e != i0 && p[e] > p1) { p1 = p[e]; i1 = e; }
  tok_e[t] = i0 | (i1 << 8);
  tok_w[t * 2]     = p0 * inv;
  tok_w[t * 2 + 1] = p1 * inv;
  atomicAdd(&lcnt[i0], 1);
  atomicAdd(&lcnt[i1], 1);
  __syncthreads();
  if (tid < NEXP) atomicAdd(&counts[tid], lcnt[tid]);
}

__global__ void route2_kernel(const int* __restrict__ counts,
                              int* __restrict__ offsets, int* __restrict__ cursor) {
  if (threadIdx.x == 0) {
    int s = 0;
    for (int e = 0; e < NEXP; ++e) { offsets[e] = s; cursor[e] = s; s += counts[e]; }
    offsets[NEXP] = s;
  }
}

__global__ void route3_kernel(const int* __restrict__ tok_e, const float* __restrict__ tok_w,
                              int* __restrict__ cursor,
                              int* __restrict__ token_list, float* __restrict__ slot_w) {
  __shared__ int lcnt[NEXP], lbase[NEXP];
  const int tid = threadIdx.x;
  const int t = blockIdx.x * 256 + tid;
  if (tid < NEXP) lcnt[tid] = 0;
  __syncthreads();
  int ee = tok_e[t];
  int e0 = ee & 255, e1 = ee >> 8;
  int li0 = atomicAdd(&lcnt[e0], 1);
  int li1 = atomicAdd(&lcnt[e1], 1);
  __syncthreads();
  if (tid < NEXP) lbase[tid] = atomicAdd(&cursor[tid], lcnt[tid]);
  __syncthreads();
  int s0 = lbase[e0] + li0;
  int s1 = lbase[e1] + li1;
  token_list[s0] = t; slot_w[s0] = tok_w[t * 2];
  token_list[s1] = t; slot_w[s1] = tok_w[t * 2 + 1];
}

__global__ void convert_x_kernel(const float4* __restrict__ x, ushort4* __restrict__ xb) {
  int i = blockIdx.x * 256 + threadIdx.x;
  float4 v = x[i];
  ushort4 o;
  o.x = f2bf(v.x); o.y = f2bf(v.y); o.z = f2bf(v.z); o.w = f2bf(v.w);
  xb[i] = o;
}

// ---------------------------------------------------------------------------
// Transpose+convert, 4-tile / single-barrier version.
// Block handles a 256(k) x 64(c) src panel = 4 sequential 64x64 tiles.
// All 16 float4 loads issued up-front (latency amortized once); ONE barrier;
// phase-2 writes 128B contiguous per thread (512B per 4-lane group).
// Exact grid: x = 128 tiles per (which,e); y = which*8+e (24).
// ---------------------------------------------------------------------------
__global__ __launch_bounds__(256, 4)
void tconv4_kernel(const float* __restrict__ w1, const float* __restrict__ w3,
                   const float* __restrict__ w2,
                   u16* __restrict__ w1t, u16* __restrict__ w3t, u16* __restrict__ w2t) {
  const int zb = blockIdx.y;
  const int which = zb >> 3;
  const int e = zb & 7;
  const int x = blockIdx.x;
  const float* src; u16* dst; int R, C, ct, kt;
  if (which == 0)      { src = w1; dst = w1t; R = HDIM; C = FDIM; ct = x & 15; kt = x >> 4; }
  else if (which == 1) { src = w3; dst = w3t; R = HDIM; C = FDIM; ct = x & 15; kt = x >> 4; }
  else                 { src = w2; dst = w2t; R = FDIM; C = HDIM; ct = x & 31; kt = x >> 5; }
  const size_t msz = (size_t)HDIM * FDIM;
  src += (size_t)e * msz;
  dst += (size_t)e * msz;
  const int r0 = kt * 256;      // k offset (src row)
  const int c0 = ct * 64;       // dst-row / src-col offset

  __shared__ uint32_t T[4][64 * 33];   // 33 KB, stride-33 (2-way-free banks)
  const int t = threadIdx.x;

  // phase 1: issue ALL loads (4 tiles x 4 float4), then cvt+pack -> LDS
  const int kp = t >> 3;        // row-pair 0..31 within tile
  const int cg = t & 7;         // col group of 8
  float4 a0[4], a1[4], b0[4], b1[4];
#pragma unroll
  for (int i = 0; i < 4; ++i) {
    const float* s0 = src + (size_t)(r0 + i * 64 + 2 * kp) * C + c0 + cg * 8;
    a0[i] = *(const float4*)(s0);
    a1[i] = *(const float4*)(s0 + 4);
    b0[i] = *(const float4*)(s0 + C);
    b1[i] = *(const float4*)(s0 + C + 4);
  }
#pragma unroll
  for (int i = 0; i < 4; ++i) {
    uint32_t* Ti = T[i];
    Ti[(cg * 8 + 0) * 33 + kp] = pack2(a0[i].x, b0[i].x);
    Ti[(cg * 8 + 1) * 33 + kp] = pack2(a0[i].y, b0[i].y);
    Ti[(cg * 8 + 2) * 33 + kp] = pack2(a0[i].z, b0[i].z);
    Ti[(cg * 8 + 3) * 33 + kp] = pack2(a0[i].w, b0[i].w);
    Ti[(cg * 8 + 4) * 33 + kp] = pack2(a1[i].x, b1[i].x);
    Ti[(cg * 8 + 5) * 33 + kp] = pack2(a1[i].y, b1[i].y);
    Ti[(cg * 8 + 6) * 33 + kp] = pack2(a1[i].z, b1[i].z);
    Ti[(cg * 8 + 7) * 33 + kp] = pack2(a1[i].w, b1[i].w);
  }
  __syncthreads();

  // phase 2: dst row c0+f, u32 segment [r0/2, r0/2+128)
  const int f  = t >> 2;        // 0..63
  const int kg = t & 3;         // 0..3
  uint32_t* drow = (uint32_t*)(dst + (size_t)(c0 + f) * R + r0);
#pragma unroll
  for (int i = 0; i < 4; ++i) {
    const uint32_t* Ti = T[i] + f * 33 + kg * 8;
    uint4 q0 = {Ti[0], Ti[1], Ti[2], Ti[3]};
    uint4 q1 = {Ti[4], Ti[5], Ti[6], Ti[7]};
    *(uint4*)(drow + i * 32 + kg * 8)     = q0;
    *(uint4*)(drow + i * 32 + kg * 8 + 4) = q1;
  }
}

// ---------------------------------------------------------------------------
// GEMM1 (verbatim round-5 measured config, 68.5us): BM=128 BN=64 BK=64,
// 4 waves, wave tile 64x32 (dual-B), single-buffer, reads -> barrier ->
// stage-issue -> MFMA (hazard-free overlap; stage drains at next top barrier).
// ---------------------------------------------------------------------------
__global__ __launch_bounds__(NTHR, 3)
void gemm1_kernel(const u16* __restrict__ Xb,
                  const u16* __restrict__ w1t,   // [E][F][H] bf16
                  const u16* __restrict__ w3t,
                  const int* __restrict__ token_list,
                  const float* __restrict__ slot_w,
                  const int* __restrict__ counts,
                  const int* __restrict__ offsets,
                  u16* __restrict__ act) {
  const int bid = blockIdx.x;
  const int e  = bid >> 8;
  const int mt = (bid >> 4) & 15;
  const int nt = bid & 15;
  const int cnt = counts[e];
  if (mt * BM >= cnt) return;
  const int off = offsets[e];
  const int tid  = threadIdx.x;
  const int lane = tid & 63;
  const int wid  = tid >> 6;
  const int wr = wid >> 1;       // 0..1 (m half)
  const int wc = wid & 1;        // 0..1 (n half)

  __shared__ u16 A_lds[BM * BK];     // 16 KB  [row][64], granule^(row&7)
  __shared__ u16 B1_lds[BN1 * BK];   // 8 KB
  __shared__ u16 B3_lds[BN1 * BK];   // 8 KB

  const u16* a_src[4];
#pragma unroll
  for (int i = 0; i < 4; ++i) {
    int row = (wid * 4 + i) * 8 + (lane >> 3);
    int mg = mt * BM + row;
    int mc = (mg < cnt) ? mg : (cnt - 1);
    int tok = token_list[off + mc];
    a_src[i] = Xb + (size_t)tok * HDIM + (((lane & 7) ^ (row & 7)) * 8);
  }
  const u16* b1_src[2];
  const u16* b3_src[2];
#pragma unroll
  for (int i = 0; i < 2; ++i) {
    int n = (wid * 2 + i) * 8 + (lane >> 3);
    size_t rowoff = ((size_t)e * FDIM + nt * BN1 + n) * HDIM + (((lane & 7) ^ (n & 7)) * 8);
    b1_src[i] = w1t + rowoff;
    b3_src[i] = w3t + rowoff;
  }

  f32x16 accg[2] = {};
  f32x16 accu[2] = {};

#pragma unroll
  for (int i = 0; i < 4; ++i) glds16(a_src[i], &A_lds[(wid * 4 + i) * 512]);
#pragma unroll
  for (int i = 0; i < 2; ++i) {
    glds16(b1_src[i], &B1_lds[(wid * 2 + i) * 512]);
    glds16(b3_src[i], &B3_lds[(wid * 2 + i) * 512]);
  }

#pragma unroll 1
  for (int t = 0; t < NK1; ++t) {
    __syncthreads();   // stage(t) drained -> tile t visible
    bf16x8 af[2][4], bg[4], bu[4];
#pragma unroll
    for (int m = 0; m < 2; ++m) {
      int R = wr * 64 + m * 32 + (lane & 31);
#pragma unroll
      for (int kk = 0; kk < 4; ++kk) {
        int gl = kk * 2 + (lane >> 5);
        af[m][kk] = *(const bf16x8*)&A_lds[R * BK + ((gl ^ (R & 7)) * 8)];
      }
    }
    {
      int R = wc * 32 + (lane & 31);
#pragma unroll
      for (int kk = 0; kk < 4; ++kk) {
        int gl = kk * 2 + (lane >> 5);
        int pos = R * BK + ((gl ^ (R & 7)) * 8);
        bg[kk] = *(const bf16x8*)&B1_lds[pos];
        bu[kk] = *(const bf16x8*)&B3_lds[pos];
      }
    }
    __syncthreads();   // all reads complete -> safe to overwrite
    if (t + 1 < NK1) { // in flight across MFMA phase; drained at next top barrier
      const int ks = (t + 1) * BK;
#pragma unroll
      for (int i = 0; i < 4; ++i) glds16(a_src[i] + ks, &A_lds[(wid * 4 + i) * 512]);
#pragma unroll
      for (int i = 0; i < 2; ++i) {
        glds16(b1_src[i] + ks, &B1_lds[(wid * 2 + i) * 512]);
        glds16(b3_src[i] + ks, &B3_lds[(wid * 2 + i) * 512]);
      }
    }
#pragma unroll
    for (int m = 0; m < 2; ++m)
#pragma unroll
      for (int kk = 0; kk < 4; ++kk) {
        accg[m] = __builtin_amdgcn_mfma_f32_32x32x16_bf16(af[m][kk], bg[kk], accg[m], 0, 0, 0);
        accu[m] = __builtin_amdgcn_mfma_f32_32x32x16_bf16(af[m][kk], bu[kk], accu[m], 0, 0, 0);
      }
  }

  // epilogue. 32x32 C/D: col=lane&31, row=(reg&3)+8*(reg>>2)+4*(lane>>5)
  const int fcol = nt * BN1 + wc * 32 + (lane & 31);
#pragma unroll
  for (int m = 0; m < 2; ++m) {
    int base = mt * BM + wr * 64 + m * 32 + 4 * (lane >> 5);
#pragma unroll
    for (int reg = 0; reg < 16; ++reg) {
      int mg = base + (reg & 3) + 8 * (reg >> 2);
      if (mg < cnt) {
        int slot = off + mg;
        float wgt = slot_w[slot];
        float g = accg[m][reg];
        float u = accu[m][reg];
        float sv = g / (1.f + __expf(-g));
        act[(size_t)slot * FDIM + fcol] = f2bf(sv * u * wgt);
      }
    }
  }
}

// ---------------------------------------------------------------------------
// GEMM2: y[token,h] += act[slot,:] @ w2t[e].  Single-B twin of gemm1's
// profile: BM=128 BN=128 BK=64, wave tile 64x64, 16 b128 reads : 16 MFMA,
// 512 real blocks. Same proven schedule.
// ---------------------------------------------------------------------------
__global__ __launch_bounds__(NTHR, 3)
void gemm2_kernel(const u16* __restrict__ act,
                  const u16* __restrict__ w2t,   // [E][H][F] bf16
                  const int* __restrict__ token_list,
                  const int* __restrict__ counts,
                  const int* __restrict__ offsets,
                  float* __restrict__ y) {
  const int bid = blockIdx.x;
  const int e  = bid >> 8;
  const int mt = (bid >> 4) & 15;
  const int nt = bid & 15;
  const int cnt = counts[e];
  if (mt * BM >= cnt) return;
  const int off = offsets[e];
  const int tid  = threadIdx.x;
  const int lane = tid & 63;
  const int wid  = tid >> 6;
  const int wr = wid >> 1;
  const int wc = wid & 1;

  __shared__ u16 A_lds[BM * BK];     // 16 KB
  __shared__ u16 B_lds[BN2 * BK];    // 16 KB

  const u16* a_src[4];
  const u16* b_src[4];
#pragma unroll
  for (int i = 0; i < 4; ++i) {
    int row = (wid * 4 + i) * 8 + (lane >> 3);
    int mg = mt * BM + row;
    int mc = (mg < cnt) ? mg : (cnt - 1);
    a_src[i] = act + (size_t)(off + mc) * FDIM + (((lane & 7) ^ (row & 7)) * 8);
    b_src[i] = w2t + ((size_t)e * HDIM + nt * BN2 + row) * FDIM + (((lane & 7) ^ (row & 7)) * 8);
  }

  f32x16 acc[2][2] = {};

#pragma unroll
  for (int i = 0; i < 4; ++i) {
    glds16(a_src[i], &A_lds[(wid * 4 + i) * 512]);
    glds16(b_src[i], &B_lds[(wid * 4 + i) * 512]);
  }

#pragma unroll 1
  for (int t = 0; t < NK2; ++t) {
    __syncthreads();
    bf16x8 af[2][4], bb[2][4];
#pragma unroll
    for (int m = 0; m < 2; ++m) {
      int R = wr * 64 + m * 32 + (lane & 31);
#pragma unroll
      for (int kk = 0; kk < 4; ++kk) {
        int gl = kk * 2 + (lane >> 5);
        af[m][kk] = *(const bf16x8*)&A_lds[R * BK + ((gl ^ (R & 7)) * 8)];
      }
    }
#pragma unroll
    for (int n = 0; n < 2; ++n) {
      int R = wc * 64 + n * 32 + (lane & 31);
#pragma unroll
      for (int kk = 0; kk < 4; ++kk) {
        int gl = kk * 2 + (lane >> 5);
        bb[n][kk] = *(const bf16x8*)&B_lds[R * BK + ((gl ^ (R & 7)) * 8)];
      }
    }
    __syncthreads();
    if (t + 1 < NK2) {
      const int ks = (t + 1) * BK;
#pragma unroll
      for (int i = 0; i < 4; ++i) {
        glds16(a_src[i] + ks, &A_lds[(wid * 4 + i) * 512]);
        glds16(b_src[i] + ks, &B_lds[(wid * 4 + i) * 512]);
      }
    }
#pragma unroll
    for (int kk = 0; kk < 4; ++kk)
#pragma unroll
      for (int m = 0; m < 2; ++m)
#pragma unroll
        for (int n = 0; n < 2; ++n)
          acc[m][n] = __builtin_amdgcn_mfma_f32_32x32x16_bf16(af[m][kk], bb[n][kk], acc[m][n], 0, 0, 0);
  }

#pragma unroll
  for (int m = 0; m < 2; ++m) {
    int base = mt * BM + wr * 64 + m * 32 + 4 * (lane >> 5);
#pragma unroll
    for (int reg = 0; reg < 16; ++reg) {
      int mg = base + (reg & 3) + 8 * (reg >> 2);
      if (mg < cnt) {
        int slot = off + mg;
        int tok = token_list[slot];
#pragma unroll
        for (int n = 0; n < 2; ++n) {
          int hcol = nt * BN2 + wc * 64 + n * 32 + (lane & 31);
          unsafeAtomicAdd(y + (size_t)tok * HDIM + hcol, acc[m][n][reg]);
        }
      }
    }
  }
}

// ---------------------------------------------------------------------------
extern "C" void kernel_launch(void* const* d_in, const int* in_sizes, int n_in,
                              void* d_out, int out_size, void* d_ws, size_t ws_size,
                              hipStream_t stream) {
  (void)in_sizes; (void)n_in; (void)out_size; (void)ws_size;
  const float* hs     = (const float*)d_in[0];
  const float* logits = (const float*)d_in[1];
  const float* w1     = (const float*)d_in[2];
  const float* w3     = (const float*)d_in[3];
  const float* w2     = (const float*)d_in[4];
  float* y = (float*)d_out;

  uint8_t* ws = (uint8_t*)d_ws;
  int*   token_list = (int*)(ws);
  float* slot_w     = (float*)(ws + (16 << 10));
  int*   counts     = (int*)(ws + (32 << 10));
  int*   offsets    = (int*)(ws + (32 << 10) + 128);
  int*   cursor     = (int*)(ws + (32 << 10) + 256);
  int*   tok_e      = (int*)(ws + (33 << 10));
  float* tok_w      = (float*)(ws + (42 << 10));
  const size_t MB = 1 << 20;
  u16*   Xb  = (u16*)(ws + (64 << 10));                 // 8 MB
  u16*   act = (u16*)(ws + (64 << 10) + 8 * MB);        // 8 MB
  u16*   w1t = (u16*)(ws + (64 << 10) + 16 * MB);       // 32 MB [E][F][H]
  u16*   w3t = (u16*)(ws + (64 << 10) + 48 * MB);       // 32 MB [E][F][H]
  u16*   w2t = (u16*)(ws + (64 << 10) + 80 * MB);       // 32 MB [E][H][F]

  hipMemsetAsync(counts, 0, NEXP * sizeof(int), stream);
  route1_kernel<<<T_TOK / 256, 256, 0, stream>>>(logits, tok_e, tok_w, counts);
  route2_kernel<<<1, 64, 0, stream>>>(counts, offsets, cursor);
  route3_kernel<<<T_TOK / 256, 256, 0, stream>>>(tok_e, tok_w, cursor, token_list, slot_w);
  convert_x_kernel<<<(T_TOK * HDIM / 4) / 256, 256, 0, stream>>>((const float4*)hs, (ushort4*)Xb);
  tconv4_kernel<<<dim3(128, 24), 256, 0, stream>>>(w1, w3, w2, w1t, w3t, w2t);
  hipMemsetAsync(d_out, 0, (size_t)T_TOK * HDIM * sizeof(float), stream);
  gemm1_kernel<<<GRID1, NTHR, 0, stream>>>(Xb, w1t, w3t, token_list, slot_w, counts, offsets, act);
  gemm2_kernel<<<GRID2, NTHR, 0, stream>>>(act, w2t, token_list, counts, offsets, y);
}